// Round 1
// baseline (30.062 us; speedup 1.0000x reference)
//
#include <hip/hip_runtime.h>

#define N_QUBITS 5
#define DIM 32
#define N_LAYERS 2

// CNOT permutation: new[i] = old[i ^ (cbit << pos_t)]
__host__ __device__ constexpr int cnot_apply(int i, int ctrl, int tgt) {
    const int pc = N_QUBITS - 1 - ctrl;
    const int pt = N_QUBITS - 1 - tgt;
    return i ^ (((i >> pc) & 1) << pt);
}

// Compose the 5 CNOTs of a layer (ctrl=q, tgt=(q+r)%5, applied q=0..4 in order):
// s_final[i] = s_before[p0(p1(p2(p3(p4(i)))))]
__host__ __device__ constexpr int layer_perm(int i, int r) {
    int idx = i;
    for (int q = N_QUBITS - 1; q >= 0; --q)
        idx = cnot_apply(idx, q, (q + r) % N_QUBITS);
    return idx;
}

__global__ __launch_bounds__(256) void vqc_kernel(
    const float* __restrict__ x,      // (B, 5)
    const float* __restrict__ w,      // (2, 5, 3)
    const float* __restrict__ fc_w,   // (8, 5)
    const float* __restrict__ fc_b,   // (8,)
    float* __restrict__ out,          // (B, 8)
    int Btot)
{
    // ---- block-uniform precompute: Rot gate coefficients into LDS ----
    __shared__ float g[N_LAYERS * N_QUBITS][8];
    __shared__ float s_fc_w[40];
    __shared__ float s_fc_b[8];

    const int t = threadIdx.x;
    if (t < N_LAYERS * N_QUBITS) {
        const float phi = w[t * 3 + 0];
        const float th  = w[t * 3 + 1];
        const float om  = w[t * 3 + 2];
        float s, c;   sincosf(0.5f * th, &s, &c);
        float sp, cp; sincosf(0.5f * (phi + om), &sp, &cp);
        float sm, cm; sincosf(0.5f * (phi - om), &sm, &cm);
        g[t][0] =  cp * c;   // g00r = cos((phi+om)/2)*cos(th/2)
        g[t][1] = -sp * c;   // g00i
        g[t][2] = -cm * s;   // g01r = -cos((phi-om)/2)*sin(th/2)
        g[t][3] = -sm * s;   // g01i
        g[t][4] =  cm * s;   // g10r
        g[t][5] = -sm * s;   // g10i
        g[t][6] =  cp * c;   // g11r
        g[t][7] =  sp * c;   // g11i
    } else if (t >= 16 && t < 56) {
        s_fc_w[t - 16] = fc_w[t - 16];
    } else if (t >= 56 && t < 64) {
        s_fc_b[t - 56] = fc_b[t - 56];
    }
    __syncthreads();

    const int b = blockIdx.x * 256 + t;
    if (b >= Btot) return;

    // ---- load x and build RX product state by doubling ----
    const float* xp = x + (size_t)b * N_QUBITS;
    float cq[N_QUBITS], sq[N_QUBITS];
#pragma unroll
    for (int q = 0; q < N_QUBITS; ++q) {
        const float xv = xp[q];
        sincosf(0.5f * xv, &sq[q], &cq[q]);
    }

    float sr[DIM], si[DIM];
    sr[0] = 1.0f; si[0] = 0.0f;
    // state = ⊗_q (c|0> - i s|1>), qubit q at bit (4-q)
#pragma unroll
    for (int q = 0; q < N_QUBITS; ++q) {
        const int stride = 1 << (N_QUBITS - 1 - q);
        const float cc = cq[q], ss = sq[q];
#pragma unroll
        for (int k = 0; k < (1 << q); ++k) {
            const int m = k * (stride << 1);
            const float ar = sr[m], ai = si[m];
            sr[m + stride] =  ss * ai;   // b = -i*s*a
            si[m + stride] = -ss * ar;
            sr[m] = cc * ar;
            si[m] = cc * ai;
        }
    }

    // ---- layers: 5 Rot gates + composed CNOT permutation ----
#pragma unroll
    for (int l = 0; l < N_LAYERS; ++l) {
#pragma unroll
        for (int q = 0; q < N_QUBITS; ++q) {
            const int gi = l * N_QUBITS + q;
            const float g00r = g[gi][0], g00i = g[gi][1];
            const float g01r = g[gi][2], g01i = g[gi][3];
            const float g10r = g[gi][4], g10i = g[gi][5];
            const float g11r = g[gi][6], g11i = g[gi][7];
            const int stride = 1 << (N_QUBITS - 1 - q);
            const int mask = stride - 1;
#pragma unroll
            for (int p = 0; p < DIM / 2; ++p) {
                const int a = ((p & ~mask) << 1) | (p & mask);
                const int bidx = a + stride;
                const float ar = sr[a],    ai = si[a];
                const float br = sr[bidx], bi = si[bidx];
                sr[a]    = g00r * ar - g00i * ai + g01r * br - g01i * bi;
                si[a]    = g00r * ai + g00i * ar + g01r * bi + g01i * br;
                sr[bidx] = g10r * ar - g10i * ai + g11r * br - g11i * bi;
                si[bidx] = g10r * ai + g10i * ar + g11r * bi + g11i * br;
            }
        }
        // CNOT ring, r = l%4+1, all 5 composed at compile time (register rename)
        const int r = (l % (N_QUBITS - 1)) + 1;
        float tr[DIM], ti[DIM];
#pragma unroll
        for (int i = 0; i < DIM; ++i) {
            const int src = layer_perm(i, r);
            tr[i] = sr[src];
            ti[i] = si[src];
        }
#pragma unroll
        for (int i = 0; i < DIM; ++i) { sr[i] = tr[i]; si[i] = ti[i]; }
    }

    // ---- probs -> expvals (signs are compile-time) ----
    float ev[N_QUBITS] = {0.f, 0.f, 0.f, 0.f, 0.f};
#pragma unroll
    for (int i = 0; i < DIM; ++i) {
        const float p = sr[i] * sr[i] + si[i] * si[i];
#pragma unroll
        for (int q = 0; q < N_QUBITS; ++q) {
            if ((i >> (N_QUBITS - 1 - q)) & 1) ev[q] -= p; else ev[q] += p;
        }
    }

    // ---- FC: out[b,j] = sum_q ev[q]*fc_w[j,q] + fc_b[j] ----
    float o[8];
#pragma unroll
    for (int j = 0; j < 8; ++j) {
        float acc = s_fc_b[j];
#pragma unroll
        for (int q = 0; q < N_QUBITS; ++q) acc += ev[q] * s_fc_w[j * N_QUBITS + q];
        o[j] = acc;
    }
    float4* op = (float4*)(out + (size_t)b * 8);
    op[0] = make_float4(o[0], o[1], o[2], o[3]);
    op[1] = make_float4(o[4], o[5], o[6], o[7]);
}

extern "C" void kernel_launch(void* const* d_in, const int* in_sizes, int n_in,
                              void* d_out, int out_size, void* d_ws, size_t ws_size,
                              hipStream_t stream) {
    const float* x    = (const float*)d_in[0];
    const float* w    = (const float*)d_in[1];
    const float* fc_w = (const float*)d_in[2];
    const float* fc_b = (const float*)d_in[3];
    float* out = (float*)d_out;

    const int Btot = in_sizes[0] / N_QUBITS;   // 262144
    const int grid = (Btot + 255) / 256;
    hipLaunchKernelGGL(vqc_kernel, dim3(grid), dim3(256), 0, stream,
                       x, w, fc_w, fc_b, out, Btot);
}

// Round 2
// 20.444 us; speedup vs baseline: 1.4705x; 1.4705x over previous
//
#include <hip/hip_runtime.h>

typedef float f2 __attribute__((ext_vector_type(2)));

#define N_QUBITS 5
#define DIM 32
#define N_LAYERS 2

// CNOT permutation: new[i] = old[i ^ (cbit << pos_t)]
__host__ __device__ constexpr int cnot_apply(int i, int ctrl, int tgt) {
    const int pc = N_QUBITS - 1 - ctrl;
    const int pt = N_QUBITS - 1 - tgt;
    return i ^ (((i >> pc) & 1) << pt);
}

// Compose the 5 CNOTs of a layer (ctrl=q, tgt=(q+r)%5, applied q=0..4):
// s_final[i] = s_before[p0(p1(p2(p3(p4(i)))))]
__host__ __device__ constexpr int layer_perm(int i, int r) {
    int idx = i;
    for (int q = N_QUBITS - 1; q >= 0; --q)
        idx = cnot_apply(idx, q, (q + r) % N_QUBITS);
    return idx;
}

__global__ __launch_bounds__(256, 4) void vqc_kernel(
    const float* __restrict__ x,      // (B, 5)
    const float* __restrict__ w,      // (2, 5, 3)
    const float* __restrict__ fc_w,   // (8, 5)
    const float* __restrict__ fc_b,   // (8,)
    float* __restrict__ out,          // (B, 8)
    int Btot)
{
    // ---- block-uniform precompute: packed Rot gate coefficients ----
    // Rot = [[g00, g01],[g10, g11]] with g11=conj(g00), g10=-conj(g01).
    // Store 4 packed consts per gate:
    //   P=(g00r,g00r) Q=(-g00i,g00i) R=(g01r,g01r) S=(-g01i,g01i)
    __shared__ f2 gq[N_LAYERS * N_QUBITS][4];
    __shared__ float s_fc_w[40];
    __shared__ float s_fc_b[8];

    const int t = threadIdx.x;
    if (t < N_LAYERS * N_QUBITS) {
        const float phi = w[t * 3 + 0];
        const float th  = w[t * 3 + 1];
        const float om  = w[t * 3 + 2];
        float s, c;   sincosf(0.5f * th, &s, &c);
        float sp, cp; sincosf(0.5f * (phi + om), &sp, &cp);
        float sm, cm; sincosf(0.5f * (phi - om), &sm, &cm);
        const float g00r = cp * c, g00i = -sp * c;
        const float g01r = -cm * s, g01i = -sm * s;
        gq[t][0] = f2{ g00r,  g00r};
        gq[t][1] = f2{-g00i,  g00i};
        gq[t][2] = f2{ g01r,  g01r};
        gq[t][3] = f2{-g01i,  g01i};
    } else if (t >= 16 && t < 56) {
        s_fc_w[t - 16] = fc_w[t - 16];
    } else if (t >= 56 && t < 64) {
        s_fc_b[t - 56] = fc_b[t - 56];
    }
    __syncthreads();

    const int b = blockIdx.x * 256 + t;
    if (b >= Btot) return;

    // ---- RX product state by doubling (fast HW sincos; |x| ~ N(0,1)) ----
    const float* xp = x + (size_t)b * N_QUBITS;
    f2 st[DIM];
    st[0] = f2{1.0f, 0.0f};
#pragma unroll
    for (int q = 0; q < N_QUBITS; ++q) {
        float s, c;
        __sincosf(0.5f * xp[q], &s, &c);
        const int stride = 1 << (N_QUBITS - 1 - q);
#pragma unroll
        for (int k = 0; k < (1 << q); ++k) {
            const int m = k * (stride << 1);
            const f2 a = st[m];
            st[m + stride] = f2{s * a.y, -s * a.x};   // -i*s*a
            st[m] = a * c;
        }
    }

    // ---- layers: 5 Rot gates (packed f32) + composed CNOT perm ----
#pragma unroll
    for (int l = 0; l < N_LAYERS; ++l) {
#pragma unroll
        for (int q = 0; q < N_QUBITS; ++q) {
            const int gi = l * N_QUBITS + q;
            const f2 P = gq[gi][0], Q = gq[gi][1];
            const f2 R = gq[gi][2], S = gq[gi][3];
            const int stride = 1 << (N_QUBITS - 1 - q);
            const int mask = stride - 1;
#pragma unroll
            for (int p = 0; p < DIM / 2; ++p) {
                const int ai = ((p & ~mask) << 1) | (p & mask);
                const int bi = ai + stride;
                const f2 a = st[ai], bb = st[bi];
                const f2 as = f2{a.y, a.x};
                const f2 bs = f2{bb.y, bb.x};
                st[ai] = P * a + Q * as + R * bb + S * bs;
                st[bi] = P * bb + S * as - R * a - Q * bs;
            }
        }
        // CNOT ring, r = l%4+1, composed at compile time (register rename)
        const int r = (l % (N_QUBITS - 1)) + 1;
        f2 tmp[DIM];
#pragma unroll
        for (int i = 0; i < DIM; ++i) tmp[i] = st[layer_perm(i, r)];
#pragma unroll
        for (int i = 0; i < DIM; ++i) st[i] = tmp[i];
    }

    // ---- probs (packed) -> expvals via Walsh-Hadamard partial-sum tree ----
    float p[DIM];
#pragma unroll
    for (int i = 0; i < DIM; ++i) {
        const f2 sq = st[i] * st[i];
        p[i] = sq.x + sq.y;
    }
    // bit0 = qubit 4, bit1 = qubit 3, ... bit4 = qubit 0
    float v16[16], v8[8], v4[4], v2[2];
    float ev4 = 0.f, ev3 = 0.f, ev2 = 0.f, ev1 = 0.f, ev0;
#pragma unroll
    for (int j = 0; j < 16; ++j) { v16[j] = p[2*j] + p[2*j+1]; ev4 += p[2*j] - p[2*j+1]; }
#pragma unroll
    for (int j = 0; j < 8; ++j)  { v8[j] = v16[2*j] + v16[2*j+1]; ev3 += v16[2*j] - v16[2*j+1]; }
#pragma unroll
    for (int j = 0; j < 4; ++j)  { v4[j] = v8[2*j] + v8[2*j+1];  ev2 += v8[2*j] - v8[2*j+1]; }
#pragma unroll
    for (int j = 0; j < 2; ++j)  { v2[j] = v4[2*j] + v4[2*j+1];  ev1 += v4[2*j] - v4[2*j+1]; }
    ev0 = v2[0] - v2[1];
    const float ev[N_QUBITS] = {ev0, ev1, ev2, ev3, ev4};

    // ---- FC: out[b,j] = sum_q ev[q]*fc_w[j,q] + fc_b[j] ----
    float o[8];
#pragma unroll
    for (int j = 0; j < 8; ++j) {
        float acc = s_fc_b[j];
#pragma unroll
        for (int q = 0; q < N_QUBITS; ++q) acc += ev[q] * s_fc_w[j * N_QUBITS + q];
        o[j] = acc;
    }
    float4* op = (float4*)(out + (size_t)b * 8);
    op[0] = make_float4(o[0], o[1], o[2], o[3]);
    op[1] = make_float4(o[4], o[5], o[6], o[7]);
}

extern "C" void kernel_launch(void* const* d_in, const int* in_sizes, int n_in,
                              void* d_out, int out_size, void* d_ws, size_t ws_size,
                              hipStream_t stream) {
    const float* x    = (const float*)d_in[0];
    const float* w    = (const float*)d_in[1];
    const float* fc_w = (const float*)d_in[2];
    const float* fc_b = (const float*)d_in[3];
    float* out = (float*)d_out;

    const int Btot = in_sizes[0] / N_QUBITS;   // 262144
    const int grid = (Btot + 255) / 256;
    hipLaunchKernelGGL(vqc_kernel, dim3(grid), dim3(256), 0, stream,
                       x, w, fc_w, fc_b, out, Btot);
}